// Round 16
// baseline (77.960 us; speedup 1.0000x reference)
//
#include <hip/hip_runtime.h>

// Problem constants: B=8, S=1024, E=128, H=32, DK=4.
constexpr int kS = 1024;

typedef __fp16 fp16x2 __attribute__((ext_vector_type(2)));
typedef _Float16 half4v __attribute__((ext_vector_type(4)));
typedef _Float16 half8v __attribute__((ext_vector_type(8)));
typedef float float4v __attribute__((ext_vector_type(4)));

// ---------------------------------------------------------------------------
// Feature-map attention (R14, verified): P[q,k] = e^{q.k/2}, q.k/2 in [-2,2].
// Deg-6 Chebyshev: e^s ~= sum_n b_n s^n (abs err ~4.5e-4) ->
// P = sum_a w_a m_q^a m_k^a over 210 monomials (|a|<=6, 4 vars).
//   M[a][c]  = sum_k m_k[a]*vv_k[c]   (vv = [z,1]; col 4 = denominator)
//   num[q][c] = sum_a m_q[a] * (w_a M[a][c]);  out = num[0..3]/num[4].
// R16: featC contraction moved onto MFMA. R14's featC was LDS-issue-bound
// (210 uniform b128+b32 reads/wave ~ 3700 LDS cyc/wave ~ 25 us). One
// B-fragment read now serves 16 q-rows: 35 LDS ops/wave (105x fewer).
// ---------------------------------------------------------------------------

__device__ __forceinline__ float wcoef(int a0, int a1, int a2, int a3) {
  const float b[7] = {1.0000101f, 1.0010454f, 0.5001437f, 0.1641115f,
                      0.0413223f, 0.00972570f, 0.00156770f};
  const float f[7] = {1.f, 1.f, 2.f, 6.f, 24.f, 120.f, 720.f};
  const float p2[7] = {1.f, 2.f, 4.f, 8.f, 16.f, 32.f, 64.f};
  int n = a0 + a1 + a2 + a3;
  return b[n] * f[n] / (p2[n] * f[a0] * f[a1] * f[a2] * f[a3]);
}

// Canonical graded enumeration of the 210 monomials; all kernels share it
// so slot s <-> monomial s is consistent between MFMA A and B operands.
template <class F>
__device__ __forceinline__ void for_each_mono(float z0, float z1, float z2,
                                              float z3, F&& f) {
  int idx = 0;
  float p0 = 1.f;
#pragma unroll
  for (int a0 = 0; a0 <= 6; ++a0) {
    float p1 = p0;
#pragma unroll
    for (int a1 = 0; a1 <= 6 - a0; ++a1) {
      float p2 = p1;
#pragma unroll
      for (int a2 = 0; a2 <= 6 - a0 - a1; ++a2) {
        float p3 = p2;
#pragma unroll
        for (int a3 = 0; a3 <= 6 - a0 - a1 - a2; ++a3) {
          f(idx, p3, a0, a1, a2, a3);
          ++idx;
          p3 *= z3;
        }
        p2 *= z2;
      }
      p1 *= z1;
    }
    p0 *= z0;
  }
}

// ---------------------------------------------------------------------------
// K1: quantum encoder (analytic collapse, verified R1-R15).
// ---------------------------------------------------------------------------
__global__ __launch_bounds__(256) void qenc_kernel(
    const float4* __restrict__ x4, const float* __restrict__ qp,
    uint2* __restrict__ h16u) {
  int idx = blockIdx.x * 256 + threadIdx.x;
  float4 a = x4[idx];
  float c0 = cosf(a.x + qp[0]);
  float c1 = cosf(a.y + qp[1]);
  float c2 = cosf(a.z + qp[2]);
  float c3 = cosf(a.w + qp[3]);
  float z1 = c0 * c1;
  float z2 = z1 * c2;
  float z3 = z2 * c3;
  float z0 = c1 * c2 * c3;
  union { half4v h; uint2 u; } z;
  z.h.x = (_Float16)z0;
  z.h.y = (_Float16)z1;
  z.h.z = (_Float16)z2;
  z.h.w = (_Float16)z3;
  int b = idx >> 15;
  int s = (idx >> 5) & (kS - 1);
  int head = idx & 31;
  int bh = b * 32 + head;
  h16u[(bh << 10) + s] = z.u;
}

// ---------------------------------------------------------------------------
// K2a: M[bh][half][alpha][c] partials (verified R14).
// ---------------------------------------------------------------------------
__global__ __launch_bounds__(256) void featM_kernel(
    const _Float16* __restrict__ h16, float* __restrict__ Mpart) {
  __shared__ _Float16 sm[210][134];
  __shared__ float vv[128][4];
  const int bh = blockIdx.x >> 1;
  const int half = blockIdx.x & 1;
  const int t = threadIdx.x;
  const bool hiH = t >= 128;
  const int tok = hiH ? t - 128 : t;
  const uint2* __restrict__ hb = (const uint2*)(h16) + (bh << 10) + (half << 9);

  float acc0 = 0.f, acc1 = 0.f, acc2 = 0.f, acc3 = 0.f, acc4 = 0.f;

  for (int ch = 0; ch < 4; ++ch) {
    {
      union { uint2 u; half4v h; } uz;
      uz.u = hb[(ch << 7) + tok];
      float z0 = (float)uz.h.x, z1 = (float)uz.h.y;
      float z2 = (float)uz.h.z, z3 = (float)uz.h.w;
      if (!hiH) {
        vv[tok][0] = z0; vv[tok][1] = z1; vv[tok][2] = z2; vv[tok][3] = z3;
      }
      for_each_mono(z0, z1, z2, z3,
                    [&](int mi, float m, int, int, int, int) {
                      if (hiH ? (mi >= 105) : (mi < 105))
                        sm[mi][tok] = (_Float16)m;
                    });
    }
    __syncthreads();
    if (t < 210) {
      for (int k = 0; k < 128; ++k) {
        float m = (float)sm[t][k];
        float4 v = *(const float4*)vv[k];  // uniform -> broadcast
        acc0 += m * v.x; acc1 += m * v.y;
        acc2 += m * v.z; acc3 += m * v.w;
        acc4 += m;
      }
    }
    __syncthreads();
  }
  if (t < 210) {
    float* mp = Mpart + (((bh << 1) + half) * 210 + t) * 5;
    mp[0] = acc0; mp[1] = acc1; mp[2] = acc2; mp[3] = acc3; mp[4] = acc4;
  }
}

// ---------------------------------------------------------------------------
// K2b v4: num[256 q][5] = m[256x224] @ (w*M)[224x5] via mfma_16x16x32_f16.
// Block = (bh, q-chunk 256). LDS: m4 rows padded to 29 uint4 (bank stagger);
// mwb = B-fragment table [k/8][col16][k&7] f16 (combine-verified layout),
// cols 5-15 and k>=210 explicitly zeroed (R12: no don't-care state).
// Wave: 7 hoisted B-reads + 4 tiles x (7 A-reads + 7 mfma). Epilogue: den
// from col-4 lane via shfl; col gather via 3 shfls; c==0 lanes store.
// ---------------------------------------------------------------------------
__global__ __launch_bounds__(256) void featC_kernel(
    const _Float16* __restrict__ h16, const float* __restrict__ Mpart,
    uint2* __restrict__ o16u2) {
  __shared__ uint4 m4[256][29];
  __shared__ uint4 mwb4[448];
  const int t = threadIdx.x;
  const int bh = blockIdx.x >> 2;
  const int qc = blockIdx.x & 3;

  // phase 0: zero the whole B table (7168 B)
  if (t < 224) {
    mwb4[t] = make_uint4(0u, 0u, 0u, 0u);
    mwb4[t + 224] = make_uint4(0u, 0u, 0u, 0u);
  }
  __syncthreads();

  // phase 0b: B[k=t][col c] = f16(w_t * (Mpart_h0 + Mpart_h1)), c = 0..4
  if (t < 210) {
    float w = 0.f;
    for_each_mono(1.f, 1.f, 1.f, 1.f,
                  [&](int mi, float, int a0, int a1, int a2, int a3) {
                    if (mi == t) w = wcoef(a0, a1, a2, a3);
                  });
    const float* p0 = Mpart + ((bh << 1) * 210 + t) * 5;
    const float* p1 = p0 + 210 * 5;
    ushort* mb = (ushort*)mwb4;
    int base = ((t >> 3) << 7) + (t & 7);
#pragma unroll
    for (int c = 0; c < 5; ++c) {
      union { _Float16 h; ushort u; } cv;
      cv.h = (_Float16)(w * (p0[c] + p1[c]));
      mb[base + (c << 3)] = cv.u;
    }
  }

  // phase 1: monomial row for q = qc*256 + t, packed f16, 28 groups of 8
  {
    union { uint2 u; half4v h; } uz;
    uz.u = ((const uint2*)h16)[(bh << 10) + (qc << 8) + t];
    float z0 = (float)uz.h.x, z1 = (float)uz.h.y;
    float z2 = (float)uz.h.z, z3 = (float)uz.h.w;
    uint pk[4];
    float prevm = 0.f;
    for_each_mono(z0, z1, z2, z3,
                  [&](int mi, float m, int, int, int, int) {
                    if (mi & 1) {
                      union { fp16x2 f; uint u; } cv;
                      cv.f = __builtin_amdgcn_cvt_pkrtz(prevm, m);
                      pk[(mi >> 1) & 3] = cv.u;  // static idx after unroll
                      if ((mi & 7) == 7)
                        m4[t][mi >> 3] = make_uint4(pk[0], pk[1], pk[2], pk[3]);
                    } else {
                      prevm = m;
                    }
                  });
    m4[t][26] = make_uint4(pk[0], 0u, 0u, 0u);  // m208,m209 + zero pad
    m4[t][27] = make_uint4(0u, 0u, 0u, 0u);     // k 216-223 zero
  }
  __syncthreads();

  // phase 2: MFMA tiles
  const int lane = t & 63;
  const int wv = t >> 6;
  const int c = lane & 15, g = lane >> 4;
  union U4H { uint4 u; half8v h; };
  U4H ub[7];
#pragma unroll
  for (int kt = 0; kt < 7; ++kt) ub[kt].u = mwb4[(((kt << 2) + g) << 4) + c];
  const int b_ = bh >> 5, head = bh & 31;
#pragma unroll
  for (int i = 0; i < 4; ++i) {
    const int T = (wv << 2) + i;
    float4v acc = {};
#pragma unroll
    for (int kt = 0; kt < 7; ++kt) {
      U4H ua;
      ua.u = m4[(T << 4) + c][(kt << 2) + g];
      acc = __builtin_amdgcn_mfma_f32_16x16x32_f16(ua.h, ub[kt].h, acc, 0, 0, 0);
    }
#pragma unroll
    for (int r = 0; r < 4; ++r) {
      float den = __shfl(acc[r], (lane & 48) | 4);
      float nv = acc[r] / den;
      float n1 = __shfl(nv, (lane & 48) | 1);
      float n2 = __shfl(nv, (lane & 48) | 2);
      float n3 = __shfl(nv, (lane & 48) | 3);
      if (c == 0) {
        union { fp16x2 p[2]; uint2 u; } res;
        res.p[0] = __builtin_amdgcn_cvt_pkrtz(nv, n1);
        res.p[1] = __builtin_amdgcn_cvt_pkrtz(n2, n3);
        int qg = (qc << 8) + (T << 4) + (g << 2) + r;
        o16u2[(((b_ << 10) + qg) << 5) + head] = res.u;
      }
    }
  }
}

// ---------------------------------------------------------------------------
// K0: pack W into B-fragment layout wtb[e>>3][col][e&7] (f16).
// ---------------------------------------------------------------------------
__global__ __launch_bounds__(256) void wtb_kernel(
    const float* __restrict__ W, _Float16* __restrict__ wtb) {
  int i = blockIdx.x * 256 + threadIdx.x;  // 16384
  int col = i >> 7, e = i & 127;
  wtb[((e >> 3) << 10) + (col << 3) + (e & 7)] = (_Float16)W[i];
}

// ---------------------------------------------------------------------------
// K3: combine GEMM out[8192][128] = o16 @ W^T via mfma_f32_16x16x32_f16.
// (verified R6-R15: ~3 us)
// ---------------------------------------------------------------------------
__global__ __launch_bounds__(256) void combine_kernel(
    const _Float16* __restrict__ o16, const _Float16* __restrict__ wtb,
    float* __restrict__ out) {
  const int lane = threadIdx.x & 63;
  const int wv = threadIdx.x >> 6;
  const int job = blockIdx.x * 4 + wv;  // 0..4095
  const int rt = job >> 3, ct = job & 7;
  const int c = lane & 15, g = lane >> 4;
  const uint4* a4 = (const uint4*)o16;
  const uint4* b4 = (const uint4*)wtb;
  const int arow = (rt << 4) + c;
  union U4H { uint4 u; half8v h; };
  float4v acc = {};
#pragma unroll
  for (int t = 0; t < 4; ++t) {
    U4H ua, ub;
    ua.u = a4[(arow << 4) + (t << 2) + g];
    ub.u = b4[(((t << 2) + g) << 7) + (ct << 4) + c];
    acc = __builtin_amdgcn_mfma_f32_16x16x32_f16(ua.h, ub.h, acc, 0, 0, 0);
  }
  const int orow = (rt << 4) + (g << 2);
  const int ocol = (ct << 4) + c;
#pragma unroll
  for (int reg = 0; reg < 4; ++reg)
    out[(orow + reg) * 128 + ocol] = acc[reg];
}

extern "C" void kernel_launch(void* const* d_in, const int* in_sizes, int n_in,
                              void* d_out, int out_size, void* d_ws,
                              size_t ws_size, hipStream_t stream) {
  const float* x = (const float*)d_in[0];   // [8,1024,128] f32
  const float* qp = (const float*)d_in[1];  // [1,4] f32
  const float* W = (const float*)d_in[2];   // [128,128] f32
  float* out = (float*)d_out;               // [8,1024,128] f32

  char* ws = (char*)d_ws;
  _Float16* h16 = (_Float16*)ws;                 // [256][1024][4] f16 = 2 MB
  float* Mpart = (float*)(ws + (2 << 20));       // [256][2][210][5] f32 ~2.1MB
  _Float16* o16 = (_Float16*)(ws + (6 << 20));   // [8192][128] f16 = 2 MB
  _Float16* wtb = (_Float16*)(ws + (8 << 20));   // [16][128][8] f16 = 32 KB

  wtb_kernel<<<64, 256, 0, stream>>>(W, wtb);
  qenc_kernel<<<1024, 256, 0, stream>>>((const float4*)x, qp, (uint2*)h16);
  featM_kernel<<<512, 256, 0, stream>>>(h16, Mpart);
  featC_kernel<<<1024, 256, 0, stream>>>(h16, Mpart, (uint2*)o16);
  combine_kernel<<<1024, 256, 0, stream>>>(o16, wtb, out);
}

// Round 17
// 74.202 us; speedup vs baseline: 1.0506x; 1.0506x over previous
//
#include <hip/hip_runtime.h>

// Problem constants: B=8, S=1024, E=128, H=32, DK=4.
constexpr int kS = 1024;

typedef __fp16 fp16x2 __attribute__((ext_vector_type(2)));
typedef _Float16 half4v __attribute__((ext_vector_type(4)));
typedef _Float16 half8v __attribute__((ext_vector_type(8)));
typedef float float4v __attribute__((ext_vector_type(4)));

// ---------------------------------------------------------------------------
// Feature-map attention (R14, verified): P[q,k] = e^{q.k/2}, q.k/2 in [-2,2].
// Deg-6 Chebyshev: e^s ~= sum_n b_n s^n (abs err ~4.5e-4) ->
// P = sum_a w_a m_q^a m_k^a over 210 monomials (|a|<=6, 4 vars).
//   M[a][c]  = sum_k m_k[a]*vv_k[c]   (vv = [z,1]; col 4 = denominator)
//   num[q][c] = sum_a m_q[a] * (w_a M[a][c]);  out = num[0..3]/num[4].
// R17: both feat kernels were LDS-ISSUE-bound (featM ~25us: 256 reads/wave/
// chunk; featC ~17us: 420 uniform reads/wave). Cut op COUNTS:
//  featM: f16 monomials, XOR-swizzled 8-key groups -> 16 b128 self-row reads
//         + 64 packed-vv uniform b128 (was 128 u16 + 128 b128).
//  featC: Mw rows packed f16x8 (1 uniform b128/monomial) + 2 q-rows/thread.
// ---------------------------------------------------------------------------

__device__ __forceinline__ float wcoef(int a0, int a1, int a2, int a3) {
  const float b[7] = {1.0000101f, 1.0010454f, 0.5001437f, 0.1641115f,
                      0.0413223f, 0.00972570f, 0.00156770f};
  const float f[7] = {1.f, 1.f, 2.f, 6.f, 24.f, 120.f, 720.f};
  const float p2[7] = {1.f, 2.f, 4.f, 8.f, 16.f, 32.f, 64.f};
  int n = a0 + a1 + a2 + a3;
  return b[n] * f[n] / (p2[n] * f[a0] * f[a1] * f[a2] * f[a3]);
}

// Canonical graded enumeration of the 210 monomials; all kernels share it.
template <class F>
__device__ __forceinline__ void for_each_mono(float z0, float z1, float z2,
                                              float z3, F&& f) {
  int idx = 0;
  float p0 = 1.f;
#pragma unroll
  for (int a0 = 0; a0 <= 6; ++a0) {
    float p1 = p0;
#pragma unroll
    for (int a1 = 0; a1 <= 6 - a0; ++a1) {
      float p2 = p1;
#pragma unroll
      for (int a2 = 0; a2 <= 6 - a0 - a1; ++a2) {
        float p3 = p2;
#pragma unroll
        for (int a3 = 0; a3 <= 6 - a0 - a1 - a2; ++a3) {
          f(idx, p3, a0, a1, a2, a3);
          ++idx;
          p3 *= z3;
        }
        p2 *= z2;
      }
      p1 *= z1;
    }
    p0 *= z0;
  }
}

// ---------------------------------------------------------------------------
// K1: quantum encoder (analytic collapse, verified R1-R16).
// ---------------------------------------------------------------------------
__global__ __launch_bounds__(256) void qenc_kernel(
    const float4* __restrict__ x4, const float* __restrict__ qp,
    uint2* __restrict__ h16u) {
  int idx = blockIdx.x * 256 + threadIdx.x;
  float4 a = x4[idx];
  float c0 = cosf(a.x + qp[0]);
  float c1 = cosf(a.y + qp[1]);
  float c2 = cosf(a.z + qp[2]);
  float c3 = cosf(a.w + qp[3]);
  float z1 = c0 * c1;
  float z2 = z1 * c2;
  float z3 = z2 * c3;
  float z0 = c1 * c2 * c3;
  union { half4v h; uint2 u; } z;
  z.h.x = (_Float16)z0;
  z.h.y = (_Float16)z1;
  z.h.z = (_Float16)z2;
  z.h.w = (_Float16)z3;
  int b = idx >> 15;
  int s = (idx >> 5) & (kS - 1);
  int head = idx & 31;
  int bh = b * 32 + head;
  h16u[(bh << 10) + s] = z.u;
}

// ---------------------------------------------------------------------------
// K2a v2: M[bh][half][alpha][c] partials. Block = (bh, half of 512 keys),
// 4 chunks of 128 keys.
// sm[mi][col]: f16 monomials, col = ((tok>>3)^(mi&7))*8 + (tok&7) — XOR
// swizzle makes the phase-2 b128 column reads bank-spread (row stride 272B
// alone would be an 8-way conflict). vvp[64] uint4: 2 keys of packed-f16 v.
// Phase2: thread alpha reads its OWN row, 8 keys per b128 (16 reads) + 4
// uniform vv b128 per group.
// ---------------------------------------------------------------------------
__global__ __launch_bounds__(256) void featM_kernel(
    const _Float16* __restrict__ h16, float* __restrict__ Mpart) {
  __shared__ ushort sm[210][136];  // 272B rows: 16B-aligned, 17 groups
  __shared__ uint4 vvp[64];
  const int bh = blockIdx.x >> 1;
  const int half = blockIdx.x & 1;
  const int t = threadIdx.x;
  const bool hiH = t >= 128;
  const int tok = t & 127;
  const uint2* __restrict__ hb = (const uint2*)(h16) + (bh << 10) + (half << 9);

  float acc0 = 0.f, acc1 = 0.f, acc2 = 0.f, acc3 = 0.f, acc4 = 0.f;

  for (int ch = 0; ch < 4; ++ch) {
    // phase 1: monomials + packed vv for this chunk's 128 tokens
    {
      union { uint2 u; half4v h; } uz;
      uz.u = hb[(ch << 7) + tok];
      float z0 = (float)uz.h.x, z1 = (float)uz.h.y;
      float z2 = (float)uz.h.z, z3 = (float)uz.h.w;
      if (!hiH) {
        union { fp16x2 f; uint u; } p01, p23;
        p01.f = __builtin_amdgcn_cvt_pkrtz(z0, z1);
        p23.f = __builtin_amdgcn_cvt_pkrtz(z2, z3);
        uint* vw = (uint*)vvp;
        vw[(tok << 1) + 0] = p01.u;
        vw[(tok << 1) + 1] = p23.u;
      }
      const int tg = tok >> 3, tj = tok & 7;
      for_each_mono(z0, z1, z2, z3,
                    [&](int mi, float m, int, int, int, int) {
                      if (hiH ? (mi >= 105) : (mi < 105)) {
                        union { _Float16 h; ushort u; } cv;
                        cv.h = (_Float16)m;
                        sm[mi][((tg ^ (mi & 7)) << 3) | tj] = cv.u;
                      }
                    });
    }
    __syncthreads();
    // phase 2: M += (own-row monomials) . vv, 8 keys per b128
    if (t < 210) {
      const uint4* row = (const uint4*)&sm[t][0];
      const int tx = t & 7;
      for (int g8 = 0; g8 < 16; ++g8) {
        union { uint4 u; half8v h; } mk;
        mk.u = row[g8 ^ tx];
#pragma unroll
        for (int kp = 0; kp < 4; ++kp) {
          union { uint4 u; half8v h; } vq;
          vq.u = vvp[(g8 << 2) + kp];
          float mA = (float)mk.h[2 * kp];
          float mB = (float)mk.h[2 * kp + 1];
          acc0 += mA * (float)vq.h[0] + mB * (float)vq.h[4];
          acc1 += mA * (float)vq.h[1] + mB * (float)vq.h[5];
          acc2 += mA * (float)vq.h[2] + mB * (float)vq.h[6];
          acc3 += mA * (float)vq.h[3] + mB * (float)vq.h[7];
          acc4 += mA + mB;
        }
      }
    }
    __syncthreads();
  }
  if (t < 210) {
    float* mp = Mpart + (((bh << 1) + half) * 210 + t) * 5;
    mp[0] = acc0; mp[1] = acc1; mp[2] = acc2; mp[3] = acc3; mp[4] = acc4;
  }
}

// ---------------------------------------------------------------------------
// K2b v5: out_num[q] = m_q . Mw. Block = (bh, half of 1024 q); each thread
// owns q and q+256 (one Mw read serves 2 rows). Mw rows packed f16x8
// (cols 0-4 + zero pad) -> ONE uniform b128 per monomial. Inner a3-loop kept
// rolled (#pragma unroll 1) to stay inside the 32KB I-cache.
// ---------------------------------------------------------------------------
__global__ __launch_bounds__(256) void featC_kernel(
    const _Float16* __restrict__ h16, const float* __restrict__ Mpart,
    uint2* __restrict__ o16u2) {
  __shared__ uint4 Mwh[210];
  const int bh = blockIdx.x >> 1;
  const int qh = blockIdx.x & 1;
  const int t = threadIdx.x;

  if (t < 210) {
    float w = 0.f;
    for_each_mono(1.f, 1.f, 1.f, 1.f,
                  [&](int mi, float, int a0, int a1, int a2, int a3) {
                    if (mi == t) w = wcoef(a0, a1, a2, a3);
                  });
    const float* p0 = Mpart + ((bh << 1) * 210 + t) * 5;
    const float* p1 = p0 + 210 * 5;
    float c0 = w * (p0[0] + p1[0]);
    float c1 = w * (p0[1] + p1[1]);
    float c2 = w * (p0[2] + p1[2]);
    float c3 = w * (p0[3] + p1[3]);
    float c4 = w * (p0[4] + p1[4]);
    union { fp16x2 f; uint u; } u01, u23, u4z;
    u01.f = __builtin_amdgcn_cvt_pkrtz(c0, c1);
    u23.f = __builtin_amdgcn_cvt_pkrtz(c2, c3);
    u4z.f = __builtin_amdgcn_cvt_pkrtz(c4, 0.f);
    Mwh[t] = make_uint4(u01.u, u23.u, u4z.u, 0u);
  }
  __syncthreads();

  const int q0 = (qh << 9) + t;  // second row: q0 + 256
  const uint2* hz = (const uint2*)h16 + (bh << 10);
  union { uint2 u; half4v h; } ua, ub;
  ua.u = hz[q0];
  ub.u = hz[q0 + 256];
  float xa0 = (float)ua.h.x, xa1 = (float)ua.h.y;
  float xa2 = (float)ua.h.z, xa3 = (float)ua.h.w;
  float xb0 = (float)ub.h.x, xb1 = (float)ub.h.y;
  float xb2 = (float)ub.h.z, xb3 = (float)ub.h.w;

  float nA0 = 0.f, nA1 = 0.f, nA2 = 0.f, nA3 = 0.f, nA4 = 0.f;
  float nB0 = 0.f, nB1 = 0.f, nB2 = 0.f, nB3 = 0.f, nB4 = 0.f;

  int idx = 0;
  float pa0 = 1.f, pb0 = 1.f;
#pragma unroll
  for (int a0 = 0; a0 <= 6; ++a0) {
    float pa1 = pa0, pb1 = pb0;
#pragma unroll
    for (int a1 = 0; a1 <= 6 - a0; ++a1) {
      float pa2 = pa1, pb2 = pb1;
#pragma unroll
      for (int a2 = 0; a2 <= 6 - a0 - a1; ++a2) {
        float pa3 = pa2, pb3 = pb2;
        const int n3 = 6 - a0 - a1 - a2;
#pragma unroll 1
        for (int a3 = 0; a3 <= n3; ++a3) {
          union { uint4 u; half8v h; } M;
          M.u = Mwh[idx];
          float M0 = (float)M.h[0], M1 = (float)M.h[1], M2 = (float)M.h[2];
          float M3 = (float)M.h[3], M4 = (float)M.h[4];
          nA0 += pa3 * M0; nA1 += pa3 * M1; nA2 += pa3 * M2;
          nA3 += pa3 * M3; nA4 += pa3 * M4;
          nB0 += pb3 * M0; nB1 += pb3 * M1; nB2 += pb3 * M2;
          nB3 += pb3 * M3; nB4 += pb3 * M4;
          ++idx;
          pa3 *= xa3; pb3 *= xb3;
        }
        pa2 *= xa2; pb2 *= xb2;
      }
      pa1 *= xa1; pb1 *= xb1;
    }
    pa0 *= xa0; pb0 *= xb0;
  }

  const int b_ = bh >> 5, head = bh & 31;
  {
    float inv = 1.0f / nA4;
    union { fp16x2 p[2]; uint2 u; } res;
    res.p[0] = __builtin_amdgcn_cvt_pkrtz(nA0 * inv, nA1 * inv);
    res.p[1] = __builtin_amdgcn_cvt_pkrtz(nA2 * inv, nA3 * inv);
    o16u2[(((b_ << 10) + q0) << 5) + head] = res.u;
  }
  {
    float inv = 1.0f / nB4;
    union { fp16x2 p[2]; uint2 u; } res;
    res.p[0] = __builtin_amdgcn_cvt_pkrtz(nB0 * inv, nB1 * inv);
    res.p[1] = __builtin_amdgcn_cvt_pkrtz(nB2 * inv, nB3 * inv);
    o16u2[(((b_ << 10) + q0 + 256) << 5) + head] = res.u;
  }
}

// ---------------------------------------------------------------------------
// K0: pack W into B-fragment layout wtb[e>>3][col][e&7] (f16).
// ---------------------------------------------------------------------------
__global__ __launch_bounds__(256) void wtb_kernel(
    const float* __restrict__ W, _Float16* __restrict__ wtb) {
  int i = blockIdx.x * 256 + threadIdx.x;  // 16384
  int col = i >> 7, e = i & 127;
  wtb[((e >> 3) << 10) + (col << 3) + (e & 7)] = (_Float16)W[i];
}

// ---------------------------------------------------------------------------
// K3: combine GEMM out[8192][128] = o16 @ W^T via mfma_f32_16x16x32_f16.
// (verified R6-R16: ~3 us)
// ---------------------------------------------------------------------------
__global__ __launch_bounds__(256) void combine_kernel(
    const _Float16* __restrict__ o16, const _Float16* __restrict__ wtb,
    float* __restrict__ out) {
  const int lane = threadIdx.x & 63;
  const int wv = threadIdx.x >> 6;
  const int job = blockIdx.x * 4 + wv;  // 0..4095
  const int rt = job >> 3, ct = job & 7;
  const int c = lane & 15, g = lane >> 4;
  const uint4* a4 = (const uint4*)o16;
  const uint4* b4 = (const uint4*)wtb;
  const int arow = (rt << 4) + c;
  union U4H { uint4 u; half8v h; };
  float4v acc = {};
#pragma unroll
  for (int t = 0; t < 4; ++t) {
    U4H ua, ub;
    ua.u = a4[(arow << 4) + (t << 2) + g];
    ub.u = b4[(((t << 2) + g) << 7) + (ct << 4) + c];
    acc = __builtin_amdgcn_mfma_f32_16x16x32_f16(ua.h, ub.h, acc, 0, 0, 0);
  }
  const int orow = (rt << 4) + (g << 2);
  const int ocol = (ct << 4) + c;
#pragma unroll
  for (int reg = 0; reg < 4; ++reg)
    out[(orow + reg) * 128 + ocol] = acc[reg];
}

extern "C" void kernel_launch(void* const* d_in, const int* in_sizes, int n_in,
                              void* d_out, int out_size, void* d_ws,
                              size_t ws_size, hipStream_t stream) {
  const float* x = (const float*)d_in[0];   // [8,1024,128] f32
  const float* qp = (const float*)d_in[1];  // [1,4] f32
  const float* W = (const float*)d_in[2];   // [128,128] f32
  float* out = (float*)d_out;               // [8,1024,128] f32

  char* ws = (char*)d_ws;
  _Float16* h16 = (_Float16*)ws;                 // [256][1024][4] f16 = 2 MB
  float* Mpart = (float*)(ws + (2 << 20));       // [256][2][210][5] f32 ~2.1MB
  _Float16* o16 = (_Float16*)(ws + (6 << 20));   // [8192][128] f16 = 2 MB
  _Float16* wtb = (_Float16*)(ws + (8 << 20));   // [16][128][8] f16 = 32 KB

  wtb_kernel<<<64, 256, 0, stream>>>(W, wtb);
  qenc_kernel<<<1024, 256, 0, stream>>>((const float4*)x, qp, (uint2*)h16);
  featM_kernel<<<512, 256, 0, stream>>>(h16, Mpart);
  featC_kernel<<<512, 256, 0, stream>>>(h16, Mpart, (uint2*)o16);
  combine_kernel<<<1024, 256, 0, stream>>>(o16, wtb, out);
}